// Round 6
// baseline (252.069 us; speedup 1.0000x reference)
//
#include <hip/hip_runtime.h>
#include <hip/hip_bf16.h>

// DotAttention pooled, SINGLE fused kernel:
//   out[b,d] = sum_t c[b,t]*V[b,t,d],
//   c[b,t] = sum_q exp(s[q,t])/l_q (no-max softmax: s~N(0,1), exp safe),
//   s = (Q K^T)/16.
// Phase 1 (all 512 blocks, one per (b, q-tile of 128)): QK^T bf16 MFMA with
//   K fp32->bf16 LDS ping-pong staging; per-block c slice -> c_ws.
// Election: 4th finisher per batch (device-scope counter, no spinning)
// Phase 2 (128 elected blocks): c totals + float4 AV sweep -> out[b,:].

typedef __bf16 bf16x8 __attribute__((ext_vector_type(8)));
typedef float  f32x4  __attribute__((ext_vector_type(4)));

#define B_    128
#define Tn    512
#define Dn    256
#define SCALE 0.0625f  // 1/sqrt(256)

// LDS index (bf16 units) for (row, 16B chunk); full xor swizzle — measured
// 0 bank conflicts (R2-R5).
__device__ __forceinline__ int lidx(int row, int ch) {
  return row * 256 + (((ch ^ row) & 31) << 3);
}

// K tile staging: 64x256 fp32 (row stride 256) -> bf16 LDS. 512 threads,
// 4 chunks of 8 floats each.
__device__ __forceinline__ void kload(const float* __restrict__ src, int tid,
                                      float4* pre) {
#pragma unroll
  for (int i = 0; i < 4; ++i) {
    int u = i * 512 + tid;
    int row = u >> 5, ch = u & 31;
    const float4* p = (const float4*)(src + row * 256 + ch * 8);
    pre[2 * i]     = p[0];
    pre[2 * i + 1] = p[1];
  }
}

__device__ __forceinline__ void kstore(__bf16* dst, int tid,
                                       const float4* pre) {
#pragma unroll
  for (int i = 0; i < 4; ++i) {
    int u = i * 512 + tid;
    int row = u >> 5, ch = u & 31;
    float4 v0 = pre[2 * i], v1 = pre[2 * i + 1];
    bf16x8 w;
    w[0] = (__bf16)v0.x; w[1] = (__bf16)v0.y;
    w[2] = (__bf16)v0.z; w[3] = (__bf16)v0.w;
    w[4] = (__bf16)v1.x; w[5] = (__bf16)v1.y;
    w[6] = (__bf16)v1.z; w[7] = (__bf16)v1.w;
    *(bf16x8*)(dst + lidx(row, ch)) = w;
  }
}

__global__ void __launch_bounds__(512) attn_fused(
    const float* __restrict__ inputs, const float* __restrict__ query,
    float* __restrict__ out, float* __restrict__ c_ws,
    unsigned int* __restrict__ done) {
  __shared__ __bf16 Kb[2][64 * 256];  // 2 x 32 KB ping-pong
  __shared__ unsigned int prev_s;

  const int tid  = threadIdx.x;
  const int bidx = blockIdx.x;
  const int b  = bidx & 127;  // same-batch blocks 128 apart -> same XCD
  const int qt = bidx >> 7;   // 0..3 (128 q each)

  const float* qsrc = query  + ((size_t)b * 512 + (size_t)qt * 128) * Dn;
  const float* ksrc = inputs + (size_t)b * Tn * Dn;

  const int wave = tid >> 6, lane = tid & 63;
  const int quad = lane >> 4, l15 = lane & 15;

  // ---- phase 1: QK^T ----
  float4 pre[8];
  kload(ksrc, tid, pre);  // K tile 0

  // A-frags straight from global fp32 (tile-invariant, register-resident):
  // Q[wave*16 + l15][dc*32 + quad*8 + j]
  bf16x8 afrag[8];
#pragma unroll
  for (int dc = 0; dc < 8; ++dc) {
    const float4* p =
        (const float4*)(qsrc + (wave * 16 + l15) * 256 + dc * 32 + quad * 8);
    float4 v0 = p[0], v1 = p[1];
    bf16x8 w;
    w[0] = (__bf16)v0.x; w[1] = (__bf16)v0.y;
    w[2] = (__bf16)v0.z; w[3] = (__bf16)v0.w;
    w[4] = (__bf16)v1.x; w[5] = (__bf16)v1.y;
    w[6] = (__bf16)v1.z; w[7] = (__bf16)v1.w;
    afrag[dc] = w;
  }

  kstore((__bf16*)Kb[0], tid, pre);
  __syncthreads();  // K0 ready

  // acc[tt][ct]: S[q = qt*128+wave*16+quad*4+r][t = tt*64+ct*16+l15]
  f32x4 acc[8][4];
  f32x4 zero = {0.f, 0.f, 0.f, 0.f};
#pragma unroll
  for (int tt = 0; tt < 8; ++tt)
#pragma unroll
    for (int ct = 0; ct < 4; ++ct) acc[tt][ct] = zero;

#pragma unroll
  for (int tt = 0; tt < 8; ++tt) {
    if (tt < 7) kload(ksrc + (size_t)(tt + 1) * 64 * Dn, tid, pre);
    const __bf16* cur = Kb[tt & 1];
#pragma unroll
    for (int dc = 0; dc < 8; ++dc) {
#pragma unroll
      for (int ct = 0; ct < 4; ++ct) {
        bf16x8 bb =
            *(const bf16x8*)(cur + lidx(ct * 16 + l15, dc * 4 + quad));
        acc[tt][ct] = __builtin_amdgcn_mfma_f32_16x16x32_bf16(
            afrag[dc], bb, acc[tt][ct], 0, 0, 0);
      }
    }
    if (tt < 7) kstore((__bf16*)Kb[(tt + 1) & 1], tid, pre);
    __syncthreads();
  }

  // ---- epilogue: exp, per-wave row sums, column weights ----
  float rs[4] = {0.f, 0.f, 0.f, 0.f};
#pragma unroll
  for (int tt = 0; tt < 8; ++tt)
#pragma unroll
    for (int ct = 0; ct < 4; ++ct)
#pragma unroll
      for (int r = 0; r < 4; ++r) {
        float p = __expf(acc[tt][ct][r] * SCALE);
        acc[tt][ct][r] = p;
        rs[r] += p;
      }
#pragma unroll
  for (int off = 1; off <= 8; off <<= 1)
#pragma unroll
    for (int r = 0; r < 4; ++r) rs[r] += __shfl_xor(rs[r], off);
  float linv[4];
#pragma unroll
  for (int r = 0; r < 4; ++r) linv[r] = 1.f / rs[r];

  float* cpart = (float*)Kb[0];  // [8 waves][512 t] = 16 KB scratch
#pragma unroll
  for (int tt = 0; tt < 8; ++tt)
#pragma unroll
    for (int ct = 0; ct < 4; ++ct) {
      float v = acc[tt][ct][0] * linv[0] + acc[tt][ct][1] * linv[1] +
                acc[tt][ct][2] * linv[2] + acc[tt][ct][3] * linv[3];
      v += __shfl_xor(v, 16);  // sum the 4 quads (same t, different q rows)
      v += __shfl_xor(v, 32);
      if (quad == 0) cpart[wave * 512 + tt * 64 + ct * 16 + l15] = v;
    }
  __syncthreads();

  {
    float csum = 0.f;
#pragma unroll
    for (int w = 0; w < 8; ++w) csum += cpart[w * 512 + tid];
    c_ws[((size_t)qt * B_ + b) * Tn + tid] = csum;
  }

  // ---- election: 4th finisher per batch does AV ----
  __threadfence();  // release c_ws slice (device scope)
  __syncthreads();
  if (tid == 0) prev_s = atomicAdd(&done[b], 1u);
  __syncthreads();
  if (prev_s != 3u) return;
  __threadfence();  // acquire siblings' c_ws slices

  // ---- phase 2: AV for batch b ----
  float* cs   = (float*)Kb[1];        // 512 f32
  float* psum = (float*)Kb[1] + 512;  // [8][256] f32
  cs[tid] = c_ws[(size_t)(0 * B_ + b) * Tn + tid] +
            c_ws[(size_t)(1 * B_ + b) * Tn + tid] +
            c_ws[(size_t)(2 * B_ + b) * Tn + tid] +
            c_ws[(size_t)(3 * B_ + b) * Tn + tid];
  __syncthreads();

  // wave w: t rows w*64..w*64+63; lane owns d = lane*4 .. +3 (float4).
  const float4* vb =
      (const float4*)(inputs + ((size_t)b * Tn + wave * 64) * Dn) + lane;
  float ox = 0.f, oy = 0.f, oz = 0.f, ow = 0.f;
#pragma unroll 8
  for (int j = 0; j < 64; ++j) {
    float c = cs[wave * 64 + j];  // wave-uniform broadcast
    float4 v = vb[(size_t)j * 64];
    ox += c * v.x; oy += c * v.y; oz += c * v.z; ow += c * v.w;
  }
  {
    float4 t = {ox, oy, oz, ow};
    *(float4*)&psum[wave * 256 + lane * 4] = t;
  }
  __syncthreads();
  if (tid < 256) {
    float s = 0.f;
#pragma unroll
    for (int w = 0; w < 8; ++w) s += psum[w * 256 + tid];
    out[b * 256 + tid] = s;  // exclusive writer — no atomics, no memset
  }
}

extern "C" void kernel_launch(void* const* d_in, const int* in_sizes, int n_in,
                              void* d_out, int out_size, void* d_ws, size_t ws_size,
                              hipStream_t stream) {
  const float* inputs = (const float*)d_in[0];  // [B,T,D]
  const float* query  = (const float*)d_in[1];  // [B,Q,D]
  float* out  = (float*)d_out;                  // [B,D]
  float* c_ws = (float*)d_ws;                   // 4*128*512 f32 = 1 MB
  unsigned int* done =
      (unsigned int*)((char*)d_ws + (size_t)4 * B_ * Tn * sizeof(float));

  hipMemsetAsync(done, 0, B_ * sizeof(unsigned int), stream);
  attn_fused<<<dim3(512), dim3(512), 0, stream>>>(inputs, query, out, c_ws,
                                                  done);
}